// Round 8
// baseline (318.376 us; speedup 1.0000x reference)
//
#include <hip/hip_runtime.h>
#include <math.h>

#define N_CELLS 50000
#define KDIM    2000
#define KPAD    2048
#define BK      128
#define NCHUNK  16
#define TM      64
#define NTILES  782
#define NROWPAD (NTILES * TM)   // 50048

typedef unsigned short u16;
typedef unsigned int   u32;
typedef __attribute__((ext_vector_type(8))) short          bf16x8;
typedef __attribute__((ext_vector_type(8))) unsigned short u16x8;
typedef __attribute__((ext_vector_type(4))) float          f32x4;
typedef __attribute__((ext_vector_type(4))) unsigned short u16x4;

__device__ __forceinline__ u16 f2bf(float f) {
  u32 u = __builtin_bit_cast(u32, f);
  return (u16)((u + 0x7FFFu + ((u >> 16) & 1u)) >> 16);
}
__device__ __forceinline__ float bf2f(u16 h) {
  u32 u = ((u32)h) << 16;
  return __builtin_bit_cast(float, u);
}

// ---------------- workspace layout (bytes) ----------------
// W1 fragment-transposed: entry (r,k) at [ ((k>>3)*256 + r)*8 + (k&7) ]
#define WS_W1     0                     // u16, 256x2048
#define WS_W2     1048576               // u16 [256][128]
#define WS_W3     (WS_W2 + 65536)       // u16 [320][128]
#define WS_PT     (WS_W3 + 81920)       // u16 [32][64]
#define WS_PN     (WS_PT + 4096)        // f32 [32]
#define WS_B1     (WS_PN + 128)         // f32 [256]
#define WS_B2     (WS_B1 + 1024)        // f32 [256]
#define WS_B3     (WS_B2 + 1024)        // f32 [320]
#define WS_SEGSUM (WS_B3 + 1280)        // f32 [64][8]
#define WS_SEGCNT (WS_SEGSUM + 2048)    // f32 [64]
#define WS_H1G    (WS_SEGCNT + 256)     // u16 [50048][256] = 25.6 MB intermediate h1

// ---------------- rest_kernel LDS layout (same proven offsets, SA->unused) ----
#define LDS_SEG  0        // int[64]
#define LDS_H2   256      // u16 [64][264]
#define LDS_SIM  256      // f32 [64][33]   (p4-p5, over dead H2)
#define LDS_H1   34048    // u16 [64][264]  (staged from global)
#define LDS_IMP  34048    // u16 [64][264]  (p3-p5, over dead H1)
#define LDS_ZB   67840    // u16 [64][72]
#define LDS_CL   67840    // f32 [64][8]    (p5, over dead ZB)
#define LDS_ZN   77056    // f32 [64]
#define LDS_TOTAL 77312

// =======================================================================
__global__ void __launch_bounds__(256) convert_kernel(
    const float* __restrict__ enc_i_w, const float* __restrict__ imp_i_w,
    const float* __restrict__ enc_h0_w, const float* __restrict__ imp_h0_w,
    const float* __restrict__ enc_z_w, const float* __restrict__ imp_p_w,
    const float* __restrict__ protos,
    const float* __restrict__ enc_i_b, const float* __restrict__ imp_i_b,
    const float* __restrict__ enc_h0_b, const float* __restrict__ imp_h0_b,
    const float* __restrict__ enc_z_b, const float* __restrict__ imp_p_b,
    char* __restrict__ ws)
{
  u16* W1 = (u16*)(ws + WS_W1);
  u16* W2 = (u16*)(ws + WS_W2);
  u16* W3 = (u16*)(ws + WS_W3);
  u16* PT = (u16*)(ws + WS_PT);
  float* PN = (float*)(ws + WS_PN);
  float* b1 = (float*)(ws + WS_B1);
  float* b2 = (float*)(ws + WS_B2);
  float* b3 = (float*)(ws + WS_B3);

  int idx = blockIdx.x * 256 + threadIdx.x;
  if (idx < 524288) {
    int r = idx >> 11, k = idx & 2047;
    float v = 0.f;
    if (k < KDIM) v = (r < 128) ? enc_i_w[r * KDIM + k] : imp_i_w[(r - 128) * KDIM + k];
    W1[((k >> 3) * 256 + r) * 8 + (k & 7)] = f2bf(v);
  } else if (idx < 557056) {
    int j = idx - 524288; int r = j >> 7, k = j & 127;
    float v = (r < 128) ? enc_h0_w[r * 128 + k] : imp_h0_w[(r - 128) * 128 + k];
    W2[j] = f2bf(v);
  } else if (idx < 598016) {
    int j = idx - 557056; int r = j >> 7, k = j & 127;
    float v = (r < 64) ? enc_z_w[r * 128 + k] : imp_p_w[(r - 64) * 128 + k];
    W3[j] = f2bf(v);
  } else if (idx < 600064) {
    int j = idx - 598016;
    PT[j] = f2bf(protos[j]);
  } else if (idx < 600096) {
    int p = idx - 600064;
    float s = 0.f;
    for (int d = 0; d < 64; ++d) { float pb = bf2f(f2bf(protos[p * 64 + d])); s += pb * pb; }
    PN[p] = s + 0.5f;
  } else if (idx < 600352) {
    int j = idx - 600096;
    b1[j] = (j < 128) ? enc_i_b[j] : imp_i_b[j - 128];
  } else if (idx < 600608) {
    int j = idx - 600352;
    b2[j] = (j < 128) ? enc_h0_b[j] : imp_h0_b[j - 128];
  } else if (idx < 600928) {
    int j = idx - 600608;
    b3[j] = (j < 64) ? enc_z_b[j] : imp_p_b[j - 64];
  }
}

// =======================================================================
#define MFMA(a, b, c) __builtin_amdgcn_mfma_f32_16x16x32_bf16((a), (b), (c), 0, 0, 0)
#define LD8(p) (*(const bf16x8*)(const void*)(p))

#define A_GLOAD(dst_, t_) {                                                  \
  const int kb_ = (t_) * BK;                                                 \
  _Pragma("unroll")                                                          \
  for (int j_ = 0; j_ < 4; ++j_) {                                           \
    const int col_ = kb_ + (ac + 8 * j_) * 4;                                \
    dst_[j_] = (arow_ok && col_ < KDIM)                                      \
               ? __builtin_nontemporal_load((const f32x4*)(xr + col_))       \
               : f4z;                                                        \
  } }

#define A_STORE(src_, buf_) {                                                \
  u16* da_ = saB + (buf_) * (TM * BK) + ar * BK;                             \
  _Pragma("unroll")                                                          \
  for (int j_ = 0; j_ < 4; ++j_) {                                           \
    u16x4 pk_;                                                               \
    pk_[0] = f2bf(src_[j_][0]); pk_[1] = f2bf(src_[j_][1]);                  \
    pk_[2] = f2bf(src_[j_][2]); pk_[3] = f2bf(src_[j_][3]);                  \
    const int cu_ = ((ac + 8 * j_) * 4) ^ swW;                               \
    *(u16x4*)(void*)(da_ + cu_) = pk_;                                       \
  } }

#define BLOAD(t_) {                                                          \
  const int tc_ = (t_);                                                      \
  _Pragma("unroll")                                                          \
  for (int q_ = 0; q_ < 8; ++q_)                                             \
    bR[q_] = LD8(bbase + (size_t)(tc_ * 16 + (q_ >> 1) * 4) * 2048 +         \
                 (q_ & 1) * 128);                                            \
  }

#define G1_MFMA(saP_) {                                                      \
  __builtin_amdgcn_s_setprio(1);                                             \
  _Pragma("unroll")                                                          \
  for (int kk_ = 0; kk_ < 4; ++kk_) {                                        \
    const int co_ = (kk_ * 32 + l4 * 8) ^ swR;                               \
    bf16x8 af0 = LD8((saP_) + (l15)      * BK + co_);                        \
    bf16x8 af1 = LD8((saP_) + (16 + l15) * BK + co_);                        \
    bf16x8 af2 = LD8((saP_) + (32 + l15) * BK + co_);                        \
    bf16x8 af3 = LD8((saP_) + (48 + l15) * BK + co_);                        \
    acc1[0][0] = MFMA(af0, bR[kk_*2+0], acc1[0][0]);                         \
    acc1[0][1] = MFMA(af0, bR[kk_*2+1], acc1[0][1]);                         \
    acc1[1][0] = MFMA(af1, bR[kk_*2+0], acc1[1][0]);                         \
    acc1[1][1] = MFMA(af1, bR[kk_*2+1], acc1[1][1]);                         \
    acc1[2][0] = MFMA(af2, bR[kk_*2+0], acc1[2][0]);                         \
    acc1[2][1] = MFMA(af2, bR[kk_*2+1], acc1[2][1]);                         \
    acc1[3][0] = MFMA(af3, bR[kk_*2+0], acc1[3][0]);                         \
    acc1[3][1] = MFMA(af3, bR[kk_*2+1], acc1[3][1]);                         \
  }                                                                          \
  __builtin_amdgcn_s_setprio(0);                                             \
  }

// ROUND-8: GEMM1 split out. LDS drops 77->32 KB -> 3 blocks/CU
// (launch_bounds(512,6)): 768 of 782 blocks co-resident (tail 1.53->1.02
// rounds) and 3x waves to hide per-chunk vmcnt stalls. h1 -> ws (25.6MB).
__global__ void __launch_bounds__(512, 6) gemm1_kernel(
    const float* __restrict__ x, const char* __restrict__ ws,
    u16* __restrict__ h1g)
{
  __shared__ u16 saB[2 * TM * BK];    // 32 KB, XOR-swizzled dbuf
  const int tid  = threadIdx.x;
  const int wave = tid >> 6;
  const int lane = tid & 63;
  const int l15  = lane & 15;
  const int l4   = lane >> 4;
  const int row0 = blockIdx.x * TM;
  const int wn0  = wave * 32;
  const int ar = tid >> 3;
  const int ac = tid & 7;
  const int swW = (ar & 7) << 3;
  const int swR = (l15 & 7) << 3;
  const f32x4 f4z = (f32x4){0.f, 0.f, 0.f, 0.f};

  const bool arow_ok = (row0 + ar) < N_CELLS;
  const float* xr = x + (size_t)(arow_ok ? (row0 + ar) : 0) * KDIM;
  const u16* const w1t = (const u16*)(ws + WS_W1);
  const u16* const bbase = w1t + (size_t)(l4 * 256 + wn0 + l15) * 8;

  f32x4 aR[4];
  bf16x8 bR[8];
  f32x4 acc1[4][2];
#pragma unroll
  for (int m = 0; m < 4; ++m)
#pragma unroll
    for (int n = 0; n < 2; ++n) acc1[m][n] = (f32x4){0.f, 0.f, 0.f, 0.f};

  A_GLOAD(aR, 0);
  A_STORE(aR, 0);
  __syncthreads();

  int cur = 0;
  for (int t = 0; t < NCHUNK; ++t) {
    BLOAD(t);
    if (t + 1 < NCHUNK) A_GLOAD(aR, t + 1);
    G1_MFMA(saB + cur * (TM * BK));
    if (t + 1 < NCHUNK) A_STORE(aR, cur ^ 1);
    __syncthreads();
    cur ^= 1;
  }

  // epilogue: bias + leaky -> global h1 (bf16, cached stores; rows beyond
  // N_CELLS land in the padded region and are deterministic zeros@x=0)
  const float* b1 = (const float*)(ws + WS_B1);
#pragma unroll
  for (int n = 0; n < 2; ++n) {
    const int col = wn0 + n * 16 + l15;
    const float bias = b1[col];
#pragma unroll
    for (int m = 0; m < 4; ++m)
#pragma unroll
      for (int j = 0; j < 4; ++j) {
        const int row = m * 16 + l4 * 4 + j;
        float v = acc1[m][n][j] + bias;
        v = (v > 0.f) ? v : 0.01f * v;
        h1g[(size_t)(row0 + row) * 256 + col] = f2bf(v);
      }
  }
}

// =======================================================================
__global__ void __launch_bounds__(512, 4) rest_kernel(
    const u16* __restrict__ h1g, const int* __restrict__ seg,
    const char* __restrict__ ws,
    float* __restrict__ seg_sums, float* __restrict__ seg_counts)
{
  extern __shared__ char smem[];
  const int tid  = threadIdx.x;
  const int wave = tid >> 6;
  const int lane = tid & 63;
  const int l15  = lane & 15;
  const int l4   = lane >> 4;
  const int row0 = blockIdx.x * TM;
  int valid = N_CELLS - row0; if (valid > TM) valid = TM;
  const int wn0 = wave * 32;

  if (tid < TM) {
    int r = row0 + tid;
    ((int*)(smem + LDS_SEG))[tid] = (r < N_CELLS) ? seg[r] : 0;
  }

  // stage h1 tile [64][256] bf16 from global (L2/L3) into padded LDS
  u16* h1 = (u16*)(smem + LDS_H1);
  {
    const int r = tid >> 3, c0 = (tid & 7) * 32;
    const u16* src = h1g + (size_t)(row0 + r) * 256 + c0;
#pragma unroll
    for (int i = 0; i < 4; ++i) {
      u16x8 v = *(const u16x8*)(const void*)(src + i * 8);
      *(u16x8*)(void*)(h1 + r * 264 + c0 + i * 8) = v;
    }
  }
  __syncthreads();

  // ---------------- GEMM2: h2[64][256] = leaky(h1_branch @ W2^T + b2) ----------------
  u16* h2 = (u16*)(smem + LDS_H2);
  {
    const u16* W2 = (const u16*)(ws + WS_W2);
    const int branch = wave >> 2;
    f32x4 acc2[4][2];
#pragma unroll
    for (int m = 0; m < 4; ++m)
#pragma unroll
      for (int n = 0; n < 2; ++n) acc2[m][n] = (f32x4){0.f, 0.f, 0.f, 0.f};
#pragma unroll
    for (int kk = 0; kk < 4; ++kk) {
      const int ko = kk * 32 + l4 * 8;
      bf16x8 af[4], bfr[2];
#pragma unroll
      for (int m = 0; m < 4; ++m) af[m] = LD8(h1 + (m * 16 + l15) * 264 + branch * 128 + ko);
#pragma unroll
      for (int n = 0; n < 2; ++n) bfr[n] = LD8(W2 + (wn0 + n * 16 + l15) * 128 + ko);
#pragma unroll
      for (int m = 0; m < 4; ++m)
#pragma unroll
        for (int n = 0; n < 2; ++n) acc2[m][n] = MFMA(af[m], bfr[n], acc2[m][n]);
    }
    const float* b2 = (const float*)(ws + WS_B2);
#pragma unroll
    for (int n = 0; n < 2; ++n) {
      const int col = wn0 + n * 16 + l15;
      const float bias = b2[col];
#pragma unroll
      for (int m = 0; m < 4; ++m)
#pragma unroll
        for (int j = 0; j < 4; ++j) {
          const int row = m * 16 + l4 * 4 + j;
          float v = acc2[m][n][j] + bias;
          v = (v > 0.f) ? v : 0.01f * v;
          h2[row * 264 + col] = f2bf(v);
        }
    }
  }
  __syncthreads();

  // ---------------- GEMM3: imp + z ----------------
  {
    const u16* W3 = (const u16*)(ws + WS_W3);
    const float* b3 = (const float*)(ws + WS_B3);
    f32x4 acc3[4][2];
#pragma unroll
    for (int m = 0; m < 4; ++m)
#pragma unroll
      for (int n = 0; n < 2; ++n) acc3[m][n] = (f32x4){0.f, 0.f, 0.f, 0.f};
#pragma unroll
    for (int kk = 0; kk < 4; ++kk) {
      const int ko = kk * 32 + l4 * 8;
      bf16x8 af[4], bfr[2];
#pragma unroll
      for (int m = 0; m < 4; ++m) af[m] = LD8(h2 + (m * 16 + l15) * 264 + 128 + ko);
#pragma unroll
      for (int n = 0; n < 2; ++n) bfr[n] = LD8(W3 + (64 + wn0 + n * 16 + l15) * 128 + ko);
#pragma unroll
      for (int m = 0; m < 4; ++m)
#pragma unroll
        for (int n = 0; n < 2; ++n) acc3[m][n] = MFMA(af[m], bfr[n], acc3[m][n]);
    }
    u16* impL = (u16*)(smem + LDS_IMP);
#pragma unroll
    for (int n = 0; n < 2; ++n) {
      const int col = wn0 + n * 16 + l15;
      const float bias = b3[64 + col];
#pragma unroll
      for (int m = 0; m < 4; ++m)
#pragma unroll
        for (int j = 0; j < 4; ++j) {
          const int row = m * 16 + l4 * 4 + j;
          float v = acc3[m][n][j] + bias;
          impL[row * 264 + col] = f2bf(1.f / (1.f + expf(-v)));
        }
    }
    if (wave < 4) {
      f32x4 accz[4];
#pragma unroll
      for (int n = 0; n < 4; ++n) accz[n] = (f32x4){0.f, 0.f, 0.f, 0.f};
#pragma unroll
      for (int kk = 0; kk < 4; ++kk) {
        const int ko = kk * 32 + l4 * 8;
        bf16x8 a = LD8(h2 + (wave * 16 + l15) * 264 + ko);
#pragma unroll
        for (int n = 0; n < 4; ++n) {
          bf16x8 b = LD8(W3 + (n * 16 + l15) * 128 + ko);
          accz[n] = MFMA(a, b, accz[n]);
        }
      }
      u16* zb = (u16*)(smem + LDS_ZB);
      float zn[4] = {0.f, 0.f, 0.f, 0.f};
#pragma unroll
      for (int n = 0; n < 4; ++n) {
        const int col = n * 16 + l15;
        const float bias = b3[col];
#pragma unroll
        for (int j = 0; j < 4; ++j) {
          const int row = wave * 16 + l4 * 4 + j;
          float v = accz[n][j] + bias;
          v = (v > 0.f) ? v : 0.01f * v;
          zb[row * 72 + col] = f2bf(v);
          zn[j] += v * v;
        }
      }
#pragma unroll
      for (int j = 0; j < 4; ++j) {
        float v = zn[j];
        v += __shfl_xor(v, 1); v += __shfl_xor(v, 2);
        v += __shfl_xor(v, 4); v += __shfl_xor(v, 8);
        zn[j] = v;
      }
      if (l15 == 0) {
        float* znL = (float*)(smem + LDS_ZN);
#pragma unroll
        for (int j = 0; j < 4; ++j) znL[wave * 16 + l4 * 4 + j] = zn[j];
      }
    }
  }
  __syncthreads();

  // ---------------- GEMM4: sim ----------------
  if (wave < 4) {
    const u16* zb = (const u16*)(smem + LDS_ZB);
    const u16* PT = (const u16*)(ws + WS_PT);
    const float* PN = (const float*)(ws + WS_PN);
    f32x4 accs[2];
#pragma unroll
    for (int n = 0; n < 2; ++n) accs[n] = (f32x4){0.f, 0.f, 0.f, 0.f};
#pragma unroll
    for (int kk = 0; kk < 2; ++kk) {
      const int ko = kk * 32 + l4 * 8;
      bf16x8 a = LD8(zb + (wave * 16 + l15) * 72 + ko);
#pragma unroll
      for (int n = 0; n < 2; ++n) {
        bf16x8 b = LD8(PT + (n * 16 + l15) * 64 + ko);
        accs[n] = MFMA(a, b, accs[n]);
      }
    }
    const float* znL = (const float*)(smem + LDS_ZN);
    float* simL = (float*)(smem + LDS_SIM);
#pragma unroll
    for (int n = 0; n < 2; ++n) {
      const int p = n * 16 + l15;
      const float pn = PN[p];
#pragma unroll
      for (int j = 0; j < 4; ++j) {
        const int row = wave * 16 + l4 * 4 + j;
        simL[row * 33 + p] = 1.f / (znL[row] - 2.f * accs[n][j] + pn);
      }
    }
  }
  __syncthreads();

  // ---------------- c_logits -> run-leader atomics ----------------
  {
    const int r = tid >> 3, c = tid & 7;
    float* cl = (float*)(smem + LDS_CL);
    if (r < valid) {
      const float* simL = (const float*)(smem + LDS_SIM);
      const u16*  impL = (const u16*)(smem + LDS_IMP);
      float s = 0.f;
#pragma unroll
      for (int p = 0; p < 32; ++p) s += simL[r * 33 + p] * bf2f(impL[r * 264 + p * 8 + c]);
      cl[r * 8 + c] = s;
    }
    __syncthreads();
    if (r < valid) {
      const int* segL = (const int*)(smem + LDS_SEG);
      const int sg = segL[r];
      if (r == 0 || segL[r - 1] != sg) {
        float s = 0.f;
        int rr = r;
        do { s += cl[rr * 8 + c]; ++rr; } while (rr < valid && segL[rr] == sg);
        atomicAdd(&seg_sums[sg * 8 + c], s);
        if (c == 0) atomicAdd(&seg_counts[sg], (float)(rr - r));
      }
    }
  }
}

// =======================================================================
__global__ void __launch_bounds__(64) finalize_kernel(const char* __restrict__ ws,
                                                      const int* __restrict__ y,
                                                      float* __restrict__ out)
{
  const int b = threadIdx.x;
  const float* sums = (const float*)(ws + WS_SEGSUM);
  const float* cnts = (const float*)(ws + WS_SEGCNT);
  const float inv = 1.f / cnts[b];
  float lg[8];
  float m = -1e30f;
#pragma unroll
  for (int c = 0; c < 8; ++c) { lg[c] = sums[b * 8 + c] * inv; m = fmaxf(m, lg[c]); }
  float se = 0.f;
#pragma unroll
  for (int c = 0; c < 8; ++c) se += expf(lg[c] - m);
  const float lse = m + logf(se);
#pragma unroll
  for (int c = 0; c < 8; ++c) out[1 + b * 8 + c] = lg[c];
  const int yb = y[b];
  float part = -(lg[yb] - lse);
  for (int o = 1; o < 64; o <<= 1) part += __shfl_xor(part, o);
  if (b == 0) out[0] = part * (1.f / 64.f);
}

// =======================================================================
extern "C" void kernel_launch(void* const* d_in, const int* in_sizes, int n_in,
                              void* d_out, int out_size, void* d_ws, size_t ws_size,
                              hipStream_t stream)
{
  const float* x        = (const float*)d_in[0];
  const int*   y        = (const int*)d_in[1];
  const int*   seg      = (const int*)d_in[2];
  const float* enc_i_w  = (const float*)d_in[3];
  const float* enc_i_b  = (const float*)d_in[4];
  const float* enc_h0_w = (const float*)d_in[5];
  const float* enc_h0_b = (const float*)d_in[6];
  const float* enc_z_w  = (const float*)d_in[7];
  const float* enc_z_b  = (const float*)d_in[8];
  const float* imp_i_w  = (const float*)d_in[9];
  const float* imp_i_b  = (const float*)d_in[10];
  const float* imp_h0_w = (const float*)d_in[11];
  const float* imp_h0_b = (const float*)d_in[12];
  const float* imp_p_w  = (const float*)d_in[13];
  const float* imp_p_b  = (const float*)d_in[14];
  const float* protos   = (const float*)d_in[15];
  char* ws = (char*)d_ws;

  hipMemsetAsync(ws + WS_SEGSUM, 0, 2048 + 256, stream);

  convert_kernel<<<2348, 256, 0, stream>>>(
      enc_i_w, imp_i_w, enc_h0_w, imp_h0_w, enc_z_w, imp_p_w, protos,
      enc_i_b, imp_i_b, enc_h0_b, imp_h0_b, enc_z_b, imp_p_b, ws);

  gemm1_kernel<<<NTILES, 512, 0, stream>>>(x, ws, (u16*)(ws + WS_H1G));

  rest_kernel<<<NTILES, 512, LDS_TOTAL, stream>>>(
      (const u16*)(ws + WS_H1G), seg, ws,
      (float*)(ws + WS_SEGSUM), (float*)(ws + WS_SEGCNT));

  finalize_kernel<<<1, 64, 0, stream>>>(ws, y, (float*)d_out);
}

// Round 9
// 199.652 us; speedup vs baseline: 1.5947x; 1.5947x over previous
//
#include <hip/hip_runtime.h>
#include <math.h>

#define N_CELLS 50000
#define KDIM    2000
#define KPAD    2048
#define BK      128
#define NCHUNK  16
#define TM      32
#define NTILES  1563     // ceil(50000/32)

typedef unsigned short u16;
typedef unsigned int   u32;
typedef __attribute__((ext_vector_type(8))) short          bf16x8;
typedef __attribute__((ext_vector_type(4))) float          f32x4;
typedef __attribute__((ext_vector_type(4))) unsigned short u16x4;

__device__ __forceinline__ u16 f2bf(float f) {
  u32 u = __builtin_bit_cast(u32, f);
  return (u16)((u + 0x7FFFu + ((u >> 16) & 1u)) >> 16);
}
__device__ __forceinline__ float bf2f(u16 h) {
  u32 u = ((u32)h) << 16;
  return __builtin_bit_cast(float, u);
}

// ---------------- workspace layout (bytes) ----------------
// W1 fragment-transposed: entry (r,k) at [ ((k>>3)*256 + r)*8 + (k&7) ]
#define WS_W1     0                     // u16, 256x2048
#define WS_W2     1048576               // u16 [256][128]
#define WS_W3     (WS_W2 + 65536)       // u16 [320][128]
#define WS_PT     (WS_W3 + 81920)       // u16 [32][64]
#define WS_PN     (WS_PT + 4096)        // f32 [32]
#define WS_B1     (WS_PN + 128)         // f32 [256]
#define WS_B2     (WS_B1 + 1024)        // f32 [256]
#define WS_B3     (WS_B2 + 1024)        // f32 [320]
#define WS_SEGSUM (WS_B3 + 1280)        // f32 [64][8]
#define WS_SEGCNT (WS_SEGSUM + 2048)    // f32 [64]

// ---------------- LDS layout (TM=32; bytes; overlap only dead regions) ----
// p1 GEMM1: SEG SA ; p2: H1(R) H2(W) ; p3: H2(R) IMP(W) ZB(W) ZN(W)
// p4: ZB ZN -> SIM(W over dead H2) ; p5: SIM IMP SEG -> CL(over dead ZB)
#define LDS_SEG  0        // 128     int[32]
#define LDS_SA   128      // 16384   u16 [2][32][128]  (XOR-swizzled dbuf)
#define LDS_H2   128      // 16896   u16 [32][264]     (p2-p3, over dead SA)
#define LDS_SIM  128      // 4224    f32 [32][33]      (p4-p5, over dead H2)
#define LDS_H1   17152    // 16896   u16 [32][264]     (p1-p2)
#define LDS_IMP  17152    // 16896   u16 [32][264]     (p3-p5, over dead H1)
#define LDS_ZB   34048    // 4608    u16 [32][72]      (p3-p4)
#define LDS_CL   34048    // 1024    f32 [32][8]       (p5, over dead ZB)
#define LDS_ZN   38656    // 128     f32 [32]
#define LDS_TOTAL 38784   // -> 4 blocks/CU by LDS; regs (~80) allow 3

// =======================================================================
__global__ void __launch_bounds__(256) convert_kernel(
    const float* __restrict__ enc_i_w, const float* __restrict__ imp_i_w,
    const float* __restrict__ enc_h0_w, const float* __restrict__ imp_h0_w,
    const float* __restrict__ enc_z_w, const float* __restrict__ imp_p_w,
    const float* __restrict__ protos,
    const float* __restrict__ enc_i_b, const float* __restrict__ imp_i_b,
    const float* __restrict__ enc_h0_b, const float* __restrict__ imp_h0_b,
    const float* __restrict__ enc_z_b, const float* __restrict__ imp_p_b,
    char* __restrict__ ws)
{
  u16* W1 = (u16*)(ws + WS_W1);
  u16* W2 = (u16*)(ws + WS_W2);
  u16* W3 = (u16*)(ws + WS_W3);
  u16* PT = (u16*)(ws + WS_PT);
  float* PN = (float*)(ws + WS_PN);
  float* b1 = (float*)(ws + WS_B1);
  float* b2 = (float*)(ws + WS_B2);
  float* b3 = (float*)(ws + WS_B3);

  int idx = blockIdx.x * 256 + threadIdx.x;
  if (idx < 524288) {
    int r = idx >> 11, k = idx & 2047;
    float v = 0.f;
    if (k < KDIM) v = (r < 128) ? enc_i_w[r * KDIM + k] : imp_i_w[(r - 128) * KDIM + k];
    W1[((k >> 3) * 256 + r) * 8 + (k & 7)] = f2bf(v);
  } else if (idx < 557056) {
    int j = idx - 524288; int r = j >> 7, k = j & 127;
    float v = (r < 128) ? enc_h0_w[r * 128 + k] : imp_h0_w[(r - 128) * 128 + k];
    W2[j] = f2bf(v);
  } else if (idx < 598016) {
    int j = idx - 557056; int r = j >> 7, k = j & 127;
    float v = (r < 64) ? enc_z_w[r * 128 + k] : imp_p_w[(r - 64) * 128 + k];
    W3[j] = f2bf(v);
  } else if (idx < 600064) {
    int j = idx - 598016;
    PT[j] = f2bf(protos[j]);
  } else if (idx < 600096) {
    int p = idx - 600064;
    float s = 0.f;
    for (int d = 0; d < 64; ++d) { float pb = bf2f(f2bf(protos[p * 64 + d])); s += pb * pb; }
    PN[p] = s + 0.5f;
  } else if (idx < 600352) {
    int j = idx - 600096;
    b1[j] = (j < 128) ? enc_i_b[j] : imp_i_b[j - 128];
  } else if (idx < 600608) {
    int j = idx - 600352;
    b2[j] = (j < 128) ? enc_h0_b[j] : imp_h0_b[j - 128];
  } else if (idx < 600928) {
    int j = idx - 600608;
    b3[j] = (j < 64) ? enc_z_b[j] : imp_p_b[j - 64];
  }
}

// =======================================================================
#define MFMA(a, b, c) __builtin_amdgcn_mfma_f32_16x16x32_bf16((a), (b), (c), 0, 0, 0)
#define LD8(p) (*(const bf16x8*)(const void*)(p))

// TM=32 staging: 512 threads stage 32 rows x 128 cols f32->bf16.
// ar = tid>>4 (row 0..31), ac = tid&15; each thread 2 x float4.
#define A_GLOAD(dst_, t_) {                                                  \
  const int kb_ = (t_) * BK;                                                 \
  _Pragma("unroll")                                                          \
  for (int j_ = 0; j_ < 2; ++j_) {                                           \
    const int col_ = kb_ + (ac + 16 * j_) * 4;                               \
    dst_[j_] = (arow_ok && col_ < KDIM)                                      \
               ? __builtin_nontemporal_load((const f32x4*)(xr + col_))       \
               : f4z;                                                        \
  } }

#define A_STORE(src_, buf_) {                                                \
  u16* da_ = saB + (buf_) * (TM * BK) + ar * BK;                             \
  _Pragma("unroll")                                                          \
  for (int j_ = 0; j_ < 2; ++j_) {                                           \
    u16x4 pk_;                                                               \
    pk_[0] = f2bf(src_[j_][0]); pk_[1] = f2bf(src_[j_][1]);                  \
    pk_[2] = f2bf(src_[j_][2]); pk_[3] = f2bf(src_[j_][3]);                  \
    const int cu_ = ((ac + 16 * j_) * 4) ^ swW;                              \
    *(u16x4*)(void*)(da_ + cu_) = pk_;                                       \
  } }

#define BLOAD(t_) {                                                          \
  const int tc_ = (t_);                                                      \
  _Pragma("unroll")                                                          \
  for (int q_ = 0; q_ < 8; ++q_)                                             \
    bR[q_] = LD8(bbase + (size_t)(tc_ * 16 + (q_ >> 1) * 4) * 2048 +         \
                 (q_ & 1) * 128);                                            \
  }

#define G1_MFMA(saP_) {                                                      \
  __builtin_amdgcn_s_setprio(1);                                             \
  _Pragma("unroll")                                                          \
  for (int kk_ = 0; kk_ < 4; ++kk_) {                                        \
    const int co_ = (kk_ * 32 + l4 * 8) ^ swR;                               \
    bf16x8 af0 = LD8((saP_) + (l15)      * BK + co_);                        \
    bf16x8 af1 = LD8((saP_) + (16 + l15) * BK + co_);                        \
    acc1[0][0] = MFMA(af0, bR[kk_*2+0], acc1[0][0]);                         \
    acc1[0][1] = MFMA(af0, bR[kk_*2+1], acc1[0][1]);                         \
    acc1[1][0] = MFMA(af1, bR[kk_*2+0], acc1[1][0]);                         \
    acc1[1][1] = MFMA(af1, bR[kk_*2+1], acc1[1][1]);                         \
  }                                                                          \
  __builtin_amdgcn_s_setprio(0);                                             \
  }

__global__ void __launch_bounds__(512, 4) fused_main(
    const float* __restrict__ x, const int* __restrict__ seg,
    const char* __restrict__ ws,
    float* __restrict__ seg_sums, float* __restrict__ seg_counts)
{
  extern __shared__ char smem[];
  const int tid  = threadIdx.x;
  const int wave = tid >> 6;
  const int lane = tid & 63;
  const int l15  = lane & 15;
  const int l4   = lane >> 4;
  const int row0 = blockIdx.x * TM;
  int valid = N_CELLS - row0; if (valid > TM) valid = TM;
  const int wn0 = wave * 32;        // wave's output-column base (0..224)
  const int ar = tid >> 4;          // A-stage row 0..31
  const int ac = tid & 15;
  const int swW = (ar & 7) << 3;    // XOR swizzle, u16 units
  const int swR = (l15 & 7) << 3;
  const f32x4 f4z = (f32x4){0.f, 0.f, 0.f, 0.f};

  if (tid < TM) {
    int r = row0 + tid;
    ((int*)(smem + LDS_SEG))[tid] = (r < N_CELLS) ? seg[r] : 0;
  }

  // ---------------- GEMM1: h1[32][256] = leaky(x @ W1^T + b1) ----------------
  u16* const saB = (u16*)(smem + LDS_SA);
  const bool arow_ok = (row0 + ar) < N_CELLS;
  const float* xr = x + (size_t)(arow_ok ? (row0 + ar) : 0) * KDIM;
  const u16* const w1t = (const u16*)(ws + WS_W1);
  const u16* const bbase = w1t + (size_t)(l4 * 256 + wn0 + l15) * 8;

  f32x4 aR[2];
  bf16x8 bR[8];
  f32x4 acc1[2][2];
#pragma unroll
  for (int m = 0; m < 2; ++m)
#pragma unroll
    for (int n = 0; n < 2; ++n) acc1[m][n] = (f32x4){0.f, 0.f, 0.f, 0.f};

  A_GLOAD(aR, 0);
  A_STORE(aR, 0);
  __syncthreads();

  int cur = 0;
  for (int t = 0; t < NCHUNK; ++t) {
    BLOAD(t);
    if (t + 1 < NCHUNK) A_GLOAD(aR, t + 1);   // issue next A early (T14)
    G1_MFMA(saB + cur * (TM * BK));
    if (t + 1 < NCHUNK) A_STORE(aR, cur ^ 1); // vmcnt wait covered by MFMAs
    __syncthreads();
    cur ^= 1;
  }

  // h1 epilogue: bias + leaky -> bf16 LDS
  u16* h1 = (u16*)(smem + LDS_H1);
  {
    const float* b1 = (const float*)(ws + WS_B1);
#pragma unroll
    for (int n = 0; n < 2; ++n) {
      const int col = wn0 + n * 16 + l15;
      const float bias = b1[col];
#pragma unroll
      for (int m = 0; m < 2; ++m)
#pragma unroll
        for (int j = 0; j < 4; ++j) {
          const int row = m * 16 + l4 * 4 + j;
          float v = acc1[m][n][j] + bias;
          v = (v > 0.f) ? v : 0.01f * v;
          h1[row * 264 + col] = f2bf(v);
        }
    }
  }
  __syncthreads();

  // ---------------- GEMM2: h2[32][256] = leaky(h1_branch @ W2^T + b2) ----------------
  u16* h2 = (u16*)(smem + LDS_H2);
  {
    const u16* W2 = (const u16*)(ws + WS_W2);
    const int branch = wave >> 2;   // waves 0-3: enc (h1 cols 0..127), 4-7: imp
    f32x4 acc2[2][2];
#pragma unroll
    for (int m = 0; m < 2; ++m)
#pragma unroll
      for (int n = 0; n < 2; ++n) acc2[m][n] = (f32x4){0.f, 0.f, 0.f, 0.f};
#pragma unroll
    for (int kk = 0; kk < 4; ++kk) {
      const int ko = kk * 32 + l4 * 8;
      bf16x8 af[2], bfr[2];
#pragma unroll
      for (int m = 0; m < 2; ++m) af[m] = LD8(h1 + (m * 16 + l15) * 264 + branch * 128 + ko);
#pragma unroll
      for (int n = 0; n < 2; ++n) bfr[n] = LD8(W2 + (wn0 + n * 16 + l15) * 128 + ko);
#pragma unroll
      for (int m = 0; m < 2; ++m)
#pragma unroll
        for (int n = 0; n < 2; ++n) acc2[m][n] = MFMA(af[m], bfr[n], acc2[m][n]);
    }
    const float* b2 = (const float*)(ws + WS_B2);
#pragma unroll
    for (int n = 0; n < 2; ++n) {
      const int col = wn0 + n * 16 + l15;
      const float bias = b2[col];
#pragma unroll
      for (int m = 0; m < 2; ++m)
#pragma unroll
        for (int j = 0; j < 4; ++j) {
          const int row = m * 16 + l4 * 4 + j;
          float v = acc2[m][n][j] + bias;
          v = (v > 0.f) ? v : 0.01f * v;
          h2[row * 264 + col] = f2bf(v);
        }
    }
  }
  __syncthreads();

  // ---------------- GEMM3: imp = sigmoid(...); z = leaky(...) ----------------
  {
    const u16* W3 = (const u16*)(ws + WS_W3);
    const float* b3 = (const float*)(ws + WS_B3);
    f32x4 acc3[2][2];
#pragma unroll
    for (int m = 0; m < 2; ++m)
#pragma unroll
      for (int n = 0; n < 2; ++n) acc3[m][n] = (f32x4){0.f, 0.f, 0.f, 0.f};
#pragma unroll
    for (int kk = 0; kk < 4; ++kk) {
      const int ko = kk * 32 + l4 * 8;
      bf16x8 af[2], bfr[2];
#pragma unroll
      for (int m = 0; m < 2; ++m) af[m] = LD8(h2 + (m * 16 + l15) * 264 + 128 + ko);
#pragma unroll
      for (int n = 0; n < 2; ++n) bfr[n] = LD8(W3 + (64 + wn0 + n * 16 + l15) * 128 + ko);
#pragma unroll
      for (int m = 0; m < 2; ++m)
#pragma unroll
        for (int n = 0; n < 2; ++n) acc3[m][n] = MFMA(af[m], bfr[n], acc3[m][n]);
    }
    u16* impL = (u16*)(smem + LDS_IMP);
#pragma unroll
    for (int n = 0; n < 2; ++n) {
      const int col = wn0 + n * 16 + l15;
      const float bias = b3[64 + col];
#pragma unroll
      for (int m = 0; m < 2; ++m)
#pragma unroll
        for (int j = 0; j < 4; ++j) {
          const int row = m * 16 + l4 * 4 + j;
          float v = acc3[m][n][j] + bias;
          impL[row * 264 + col] = f2bf(1.f / (1.f + expf(-v)));
        }
    }
    // z: waves 0-1 compute 16 rows each, all 64 cols
    if (wave < 2) {
      f32x4 accz[4];
#pragma unroll
      for (int n = 0; n < 4; ++n) accz[n] = (f32x4){0.f, 0.f, 0.f, 0.f};
#pragma unroll
      for (int kk = 0; kk < 4; ++kk) {
        const int ko = kk * 32 + l4 * 8;
        bf16x8 a = LD8(h2 + (wave * 16 + l15) * 264 + ko);
#pragma unroll
        for (int n = 0; n < 4; ++n) {
          bf16x8 b = LD8(W3 + (n * 16 + l15) * 128 + ko);
          accz[n] = MFMA(a, b, accz[n]);
        }
      }
      u16* zb = (u16*)(smem + LDS_ZB);
      float zn[4] = {0.f, 0.f, 0.f, 0.f};
#pragma unroll
      for (int n = 0; n < 4; ++n) {
        const int col = n * 16 + l15;
        const float bias = b3[col];
#pragma unroll
        for (int j = 0; j < 4; ++j) {
          const int row = wave * 16 + l4 * 4 + j;
          float v = accz[n][j] + bias;
          v = (v > 0.f) ? v : 0.01f * v;
          zb[row * 72 + col] = f2bf(v);
          zn[j] += v * v;
        }
      }
#pragma unroll
      for (int j = 0; j < 4; ++j) {
        float v = zn[j];
        v += __shfl_xor(v, 1); v += __shfl_xor(v, 2);
        v += __shfl_xor(v, 4); v += __shfl_xor(v, 8);
        zn[j] = v;
      }
      if (l15 == 0) {
        float* znL = (float*)(smem + LDS_ZN);
#pragma unroll
        for (int j = 0; j < 4; ++j) znL[wave * 16 + l4 * 4 + j] = zn[j];
      }
    }
  }
  __syncthreads();

  // ---------------- GEMM4: sim[32][32] = 1/(|z|^2 - 2 z.p + |p|^2 + 0.5) ----------------
  if (wave < 2) {
    const u16* zb = (const u16*)(smem + LDS_ZB);
    const u16* PT = (const u16*)(ws + WS_PT);
    const float* PN = (const float*)(ws + WS_PN);
    f32x4 accs[2];
#pragma unroll
    for (int n = 0; n < 2; ++n) accs[n] = (f32x4){0.f, 0.f, 0.f, 0.f};
#pragma unroll
    for (int kk = 0; kk < 2; ++kk) {
      const int ko = kk * 32 + l4 * 8;
      bf16x8 a = LD8(zb + (wave * 16 + l15) * 72 + ko);
#pragma unroll
      for (int n = 0; n < 2; ++n) {
        bf16x8 b = LD8(PT + (n * 16 + l15) * 64 + ko);
        accs[n] = MFMA(a, b, accs[n]);
      }
    }
    const float* znL = (const float*)(smem + LDS_ZN);
    float* simL = (float*)(smem + LDS_SIM);
#pragma unroll
    for (int n = 0; n < 2; ++n) {
      const int p = n * 16 + l15;
      const float pn = PN[p];
#pragma unroll
      for (int j = 0; j < 4; ++j) {
        const int row = wave * 16 + l4 * 4 + j;
        simL[row * 33 + p] = 1.f / (znL[row] - 2.f * accs[n][j] + pn);
      }
    }
  }
  __syncthreads();

  // ---------------- c_logits -> run-leader atomics ----------------
  {
    const int r = tid >> 3, c = tid & 7;   // threads 0..255 cover 32 rows x 8 cls
    float* cl = (float*)(smem + LDS_CL);
    if (r < valid) {
      const float* simL = (const float*)(smem + LDS_SIM);
      const u16*  impL = (const u16*)(smem + LDS_IMP);
      float s = 0.f;
#pragma unroll
      for (int p = 0; p < 32; ++p) s += simL[r * 33 + p] * bf2f(impL[r * 264 + p * 8 + c]);
      cl[r * 8 + c] = s;
    }
    __syncthreads();
    if (r < valid) {
      const int* segL = (const int*)(smem + LDS_SEG);
      const int sg = segL[r];
      if (r == 0 || segL[r - 1] != sg) {   // leader of a segment run
        float s = 0.f;
        int rr = r;
        do { s += cl[rr * 8 + c]; ++rr; } while (rr < valid && segL[rr] == sg);
        atomicAdd(&seg_sums[sg * 8 + c], s);
        if (c == 0) atomicAdd(&seg_counts[sg], (float)(rr - r));
      }
    }
  }
}

// =======================================================================
__global__ void __launch_bounds__(64) finalize_kernel(const char* __restrict__ ws,
                                                      const int* __restrict__ y,
                                                      float* __restrict__ out)
{
  const int b = threadIdx.x;
  const float* sums = (const float*)(ws + WS_SEGSUM);
  const float* cnts = (const float*)(ws + WS_SEGCNT);
  const float inv = 1.f / cnts[b];
  float lg[8];
  float m = -1e30f;
#pragma unroll
  for (int c = 0; c < 8; ++c) { lg[c] = sums[b * 8 + c] * inv; m = fmaxf(m, lg[c]); }
  float se = 0.f;
#pragma unroll
  for (int c = 0; c < 8; ++c) se += expf(lg[c] - m);
  const float lse = m + logf(se);
#pragma unroll
  for (int c = 0; c < 8; ++c) out[1 + b * 8 + c] = lg[c];
  const int yb = y[b];
  float part = -(lg[yb] - lse);
  for (int o = 1; o < 64; o <<= 1) part += __shfl_xor(part, o);
  if (b == 0) out[0] = part * (1.f / 64.f);
}

// =======================================================================
extern "C" void kernel_launch(void* const* d_in, const int* in_sizes, int n_in,
                              void* d_out, int out_size, void* d_ws, size_t ws_size,
                              hipStream_t stream)
{
  const float* x        = (const float*)d_in[0];
  const int*   y        = (const int*)d_in[1];
  const int*   seg      = (const int*)d_in[2];
  const float* enc_i_w  = (const float*)d_in[3];
  const float* enc_i_b  = (const float*)d_in[4];
  const float* enc_h0_w = (const float*)d_in[5];
  const float* enc_h0_b = (const float*)d_in[6];
  const float* enc_z_w  = (const float*)d_in[7];
  const float* enc_z_b  = (const float*)d_in[8];
  const float* imp_i_w  = (const float*)d_in[9];
  const float* imp_i_b  = (const float*)d_in[10];
  const float* imp_h0_w = (const float*)d_in[11];
  const float* imp_h0_b = (const float*)d_in[12];
  const float* imp_p_w  = (const float*)d_in[13];
  const float* imp_p_b  = (const float*)d_in[14];
  const float* protos   = (const float*)d_in[15];
  char* ws = (char*)d_ws;

  hipMemsetAsync(ws + WS_SEGSUM, 0, 2048 + 256, stream);

  convert_kernel<<<2348, 256, 0, stream>>>(
      enc_i_w, imp_i_w, enc_h0_w, imp_h0_w, enc_z_w, imp_p_w, protos,
      enc_i_b, imp_i_b, enc_h0_b, imp_h0_b, enc_z_b, imp_p_b, ws);

  fused_main<<<NTILES, 512, LDS_TOTAL, stream>>>(
      x, seg, ws, (float*)(ws + WS_SEGSUM), (float*)(ws + WS_SEGCNT));

  finalize_kernel<<<1, 64, 0, stream>>>(ws, y, (float*)d_out);
}

// Round 10
// 180.793 us; speedup vs baseline: 1.7610x; 1.1043x over previous
//
#include <hip/hip_runtime.h>
#include <math.h>

#define N_CELLS 50000
#define KDIM    2000
#define KPAD    2048
#define BK      128
#define NCHUNK  16
#define TM      64

typedef unsigned short u16;
typedef unsigned int   u32;
typedef __attribute__((ext_vector_type(8))) short          bf16x8;
typedef __attribute__((ext_vector_type(4))) float          f32x4;
typedef __attribute__((ext_vector_type(4))) unsigned short u16x4;

__device__ __forceinline__ u16 f2bf(float f) {
  u32 u = __builtin_bit_cast(u32, f);
  return (u16)((u + 0x7FFFu + ((u >> 16) & 1u)) >> 16);
}
__device__ __forceinline__ float bf2f(u16 h) {
  u32 u = ((u32)h) << 16;
  return __builtin_bit_cast(float, u);
}

// ---------------- workspace layout (bytes) ----------------
// W1 fragment-transposed: entry (r,k) at [ ((k>>3)*256 + r)*8 + (k&7) ]
#define WS_W1     0                     // u16, 256x2048
#define WS_W2     1048576               // u16 [256][128]
#define WS_W3     (WS_W2 + 65536)       // u16 [320][128]
#define WS_PT     (WS_W3 + 81920)       // u16 [32][64]
#define WS_PN     (WS_PT + 4096)        // f32 [32]
#define WS_B1     (WS_PN + 128)         // f32 [256]
#define WS_B2     (WS_B1 + 1024)        // f32 [256]
#define WS_B3     (WS_B2 + 1024)        // f32 [320]
#define WS_SEGSUM (WS_B3 + 1280)        // f32 [64][8]
#define WS_SEGCNT (WS_SEGSUM + 2048)    // f32 [64]

// ---------------- LDS layout (bytes; regions overlap only when dead) ----
#define LDS_SEG  0        // int[64]
#define LDS_SA   256      // 32768   u16 [2][64][128]  (XOR-swizzled, parity dbuf)
#define LDS_H2   256      // 33792   u16 [64][264]     (p2-p3, over dead SA)
#define LDS_SIM  256      // 8448    f32 [64][33]      (p4-p5, over dead H2)
#define LDS_H1   34048    // 33792   u16 [64][264]     (p1-p2)
#define LDS_IMP  34048    // 33792   u16 [64][264]     (p3-p5, over dead H1)
#define LDS_ZB   67840    // 9216    u16 [64][72]      (p3-p4)
#define LDS_CL   67840    // 2048    f32 [64][8]       (p5, over dead ZB)
#define LDS_ZN   77056    // 256     f32 [64]
#define LDS_TOTAL 77312

// =======================================================================
__global__ void __launch_bounds__(256) convert_kernel(
    const float* __restrict__ enc_i_w, const float* __restrict__ imp_i_w,
    const float* __restrict__ enc_h0_w, const float* __restrict__ imp_h0_w,
    const float* __restrict__ enc_z_w, const float* __restrict__ imp_p_w,
    const float* __restrict__ protos,
    const float* __restrict__ enc_i_b, const float* __restrict__ imp_i_b,
    const float* __restrict__ enc_h0_b, const float* __restrict__ imp_h0_b,
    const float* __restrict__ enc_z_b, const float* __restrict__ imp_p_b,
    char* __restrict__ ws)
{
  u16* W1 = (u16*)(ws + WS_W1);
  u16* W2 = (u16*)(ws + WS_W2);
  u16* W3 = (u16*)(ws + WS_W3);
  u16* PT = (u16*)(ws + WS_PT);
  float* PN = (float*)(ws + WS_PN);
  float* b1 = (float*)(ws + WS_B1);
  float* b2 = (float*)(ws + WS_B2);
  float* b3 = (float*)(ws + WS_B3);

  int idx = blockIdx.x * 256 + threadIdx.x;
  if (idx < 524288) {
    int r = idx >> 11, k = idx & 2047;
    float v = 0.f;
    if (k < KDIM) v = (r < 128) ? enc_i_w[r * KDIM + k] : imp_i_w[(r - 128) * KDIM + k];
    W1[((k >> 3) * 256 + r) * 8 + (k & 7)] = f2bf(v);
  } else if (idx < 557056) {
    int j = idx - 524288; int r = j >> 7, k = j & 127;
    float v = (r < 128) ? enc_h0_w[r * 128 + k] : imp_h0_w[(r - 128) * 128 + k];
    W2[j] = f2bf(v);
  } else if (idx < 598016) {
    int j = idx - 557056; int r = j >> 7, k = j & 127;
    float v = (r < 64) ? enc_z_w[r * 128 + k] : imp_p_w[(r - 64) * 128 + k];
    W3[j] = f2bf(v);
  } else if (idx < 600064) {
    int j = idx - 598016;
    PT[j] = f2bf(protos[j]);
  } else if (idx < 600096) {
    int p = idx - 600064;
    float s = 0.f;
    for (int d = 0; d < 64; ++d) { float pb = bf2f(f2bf(protos[p * 64 + d])); s += pb * pb; }
    PN[p] = s + 0.5f;
  } else if (idx < 600352) {
    int j = idx - 600096;
    b1[j] = (j < 128) ? enc_i_b[j] : imp_i_b[j - 128];
  } else if (idx < 600608) {
    int j = idx - 600352;
    b2[j] = (j < 128) ? enc_h0_b[j] : imp_h0_b[j - 128];
  } else if (idx < 600928) {
    int j = idx - 600608;
    b3[j] = (j < 64) ? enc_z_b[j] : imp_p_b[j - 64];
  }
}

// =======================================================================
#define MFMA(a, b, c) __builtin_amdgcn_mfma_f32_16x16x32_bf16((a), (b), (c), 0, 0, 0)
#define LD8(p) (*(const bf16x8*)(const void*)(p))

// ROUND-10: round-7 structure + 2-deep A-prefetch (pair-unrolled, parity
// buffers, NON-persistent — rounds 5/6 proved the persistent loop, not the
// prefetch depth, caused the spill). B-loads split into 4-reg halves to cut
// peak pressure. Every A_STORE now waits on loads issued >=1 full chunk
// (~2000cy) earlier -> per-chunk HBM-latency bubble eliminated.
#define A_GLOAD(dst_, t_) {                                                  \
  const int kb_ = (t_) * BK;                                                 \
  _Pragma("unroll")                                                          \
  for (int j_ = 0; j_ < 4; ++j_) {                                           \
    const int col_ = kb_ + (ac + 8 * j_) * 4;                                \
    dst_[j_] = (arow_ok && col_ < KDIM)                                      \
               ? __builtin_nontemporal_load((const f32x4*)(xr + col_))       \
               : f4z;                                                        \
  } }

#define A_STORE(src_, buf_) {                                                \
  u16* da_ = saB + (buf_) * (TM * BK) + ar * BK;                             \
  _Pragma("unroll")                                                          \
  for (int j_ = 0; j_ < 4; ++j_) {                                           \
    u16x4 pk_;                                                               \
    pk_[0] = f2bf(src_[j_][0]); pk_[1] = f2bf(src_[j_][1]);                  \
    pk_[2] = f2bf(src_[j_][2]); pk_[3] = f2bf(src_[j_][3]);                  \
    const int cu_ = ((ac + 8 * j_) * 4) ^ swW;                               \
    *(u16x4*)(void*)(da_ + cu_) = pk_;                                       \
  } }

// half h_ covers kk = 2h, 2h+1 (4 B-fragments in bR[0..3])
#define BLOADH(t_, h_) {                                                     \
  _Pragma("unroll")                                                          \
  for (int q_ = 0; q_ < 4; ++q_)                                             \
    bR[q_] = LD8(bbase + (size_t)((t_) * 16 + ((h_) * 2 + (q_ >> 1)) * 4)    \
                 * 2048 + (q_ & 1) * 128);                                   \
  }

#define G1_MFMA_H(saP_, h_) {                                                \
  __builtin_amdgcn_s_setprio(1);                                             \
  _Pragma("unroll")                                                          \
  for (int kq_ = 0; kq_ < 2; ++kq_) {                                        \
    const int kk_ = (h_) * 2 + kq_;                                          \
    const int co_ = (kk_ * 32 + l4 * 8) ^ swR;                               \
    bf16x8 af0 = LD8((saP_) + (l15)      * BK + co_);                        \
    bf16x8 af1 = LD8((saP_) + (16 + l15) * BK + co_);                        \
    bf16x8 af2 = LD8((saP_) + (32 + l15) * BK + co_);                        \
    bf16x8 af3 = LD8((saP_) + (48 + l15) * BK + co_);                        \
    acc1[0][0] = MFMA(af0, bR[kq_*2+0], acc1[0][0]);                         \
    acc1[0][1] = MFMA(af0, bR[kq_*2+1], acc1[0][1]);                         \
    acc1[1][0] = MFMA(af1, bR[kq_*2+0], acc1[1][0]);                         \
    acc1[1][1] = MFMA(af1, bR[kq_*2+1], acc1[1][1]);                         \
    acc1[2][0] = MFMA(af2, bR[kq_*2+0], acc1[2][0]);                         \
    acc1[2][1] = MFMA(af2, bR[kq_*2+1], acc1[2][1]);                         \
    acc1[3][0] = MFMA(af3, bR[kq_*2+0], acc1[3][0]);                         \
    acc1[3][1] = MFMA(af3, bR[kq_*2+1], acc1[3][1]);                         \
  }                                                                          \
  __builtin_amdgcn_s_setprio(0);                                             \
  }

__global__ void __launch_bounds__(512, 4) fused_main(
    const float* __restrict__ x, const int* __restrict__ seg,
    const char* __restrict__ ws,
    float* __restrict__ seg_sums, float* __restrict__ seg_counts)
{
  extern __shared__ char smem[];
  const int tid  = threadIdx.x;
  const int wave = tid >> 6;
  const int lane = tid & 63;
  const int l15  = lane & 15;
  const int l4   = lane >> 4;
  const int row0 = blockIdx.x * TM;
  int valid = N_CELLS - row0; if (valid > TM) valid = TM;
  const int wn0 = wave * 32;        // wave's output-column base (0..224)
  const int ar = tid >> 3;          // A-stage row 0..63
  const int ac = tid & 7;
  const int swW = (ar & 7) << 3;    // XOR swizzle, u16 units (= (row&7)<<4 bytes)
  const int swR = (l15 & 7) << 3;
  const f32x4 f4z = (f32x4){0.f, 0.f, 0.f, 0.f};

  if (tid < TM) {
    int r = row0 + tid;
    ((int*)(smem + LDS_SEG))[tid] = (r < N_CELLS) ? seg[r] : 0;
  }

  // ---------------- GEMM1: h1[64][256] = leaky(x @ W1^T + b1) ----------------
  u16* const saB = (u16*)(smem + LDS_SA);
  const bool arow_ok = (row0 + ar) < N_CELLS;
  const float* xr = x + (size_t)(arow_ok ? (row0 + ar) : 0) * KDIM;
  const u16* const w1t = (const u16*)(ws + WS_W1);
  const u16* const bbase = w1t + (size_t)(l4 * 256 + wn0 + l15) * 8;

  f32x4 aRA[4], aRB[4];
  bf16x8 bR[4];
  f32x4 acc1[4][2];
#pragma unroll
  for (int m = 0; m < 4; ++m)
#pragma unroll
    for (int n = 0; n < 2; ++n) acc1[m][n] = (f32x4){0.f, 0.f, 0.f, 0.f};

  A_GLOAD(aRA, 0);
  A_GLOAD(aRB, 1);
  A_STORE(aRA, 0);                  // chunk0 -> buf0
  __syncthreads();

  // pair-unrolled: even chunks in buf0, odd in buf1 (parity fixed)
  for (int t = 0; t < NCHUNK; t += 2) {
    // ---- step A: compute chunk t (buf0) ----
    if (t + 2 < NCHUNK) A_GLOAD(aRA, t + 2);   // issued 1.5-2 chunks ahead of use
    BLOADH(t, 0);
    G1_MFMA_H(saB, 0);
    BLOADH(t, 1);
    G1_MFMA_H(saB, 1);
    A_STORE(aRB, 1);                // chunk t+1, loaded >=1 chunk ago -> no stall
    __syncthreads();
    // ---- step B: compute chunk t+1 (buf1) ----
    if (t + 3 < NCHUNK) A_GLOAD(aRB, t + 3);
    BLOADH(t + 1, 0);
    G1_MFMA_H(saB + TM * BK, 0);
    BLOADH(t + 1, 1);
    G1_MFMA_H(saB + TM * BK, 1);
    if (t + 2 < NCHUNK) A_STORE(aRA, 0);       // chunk t+2
    __syncthreads();
  }

  // h1 epilogue: bias + leaky -> bf16 LDS
  u16* h1 = (u16*)(smem + LDS_H1);
  {
    const float* b1 = (const float*)(ws + WS_B1);
#pragma unroll
    for (int n = 0; n < 2; ++n) {
      const int col = wn0 + n * 16 + l15;
      const float bias = b1[col];
#pragma unroll
      for (int m = 0; m < 4; ++m)
#pragma unroll
        for (int j = 0; j < 4; ++j) {
          const int row = m * 16 + l4 * 4 + j;
          float v = acc1[m][n][j] + bias;
          v = (v > 0.f) ? v : 0.01f * v;
          h1[row * 264 + col] = f2bf(v);
        }
    }
  }
  __syncthreads();

  // ---------------- GEMM2: h2[64][256] = leaky(h1_branch @ W2^T + b2) ----------------
  u16* h2 = (u16*)(smem + LDS_H2);
  {
    const u16* W2 = (const u16*)(ws + WS_W2);
    const int branch = wave >> 2;   // waves 0-3: enc (h1 cols 0..127), 4-7: imp
    f32x4 acc2[4][2];
#pragma unroll
    for (int m = 0; m < 4; ++m)
#pragma unroll
      for (int n = 0; n < 2; ++n) acc2[m][n] = (f32x4){0.f, 0.f, 0.f, 0.f};
#pragma unroll
    for (int kk = 0; kk < 4; ++kk) {
      const int ko = kk * 32 + l4 * 8;
      bf16x8 af[4], bfr[2];
#pragma unroll
      for (int m = 0; m < 4; ++m) af[m] = LD8(h1 + (m * 16 + l15) * 264 + branch * 128 + ko);
#pragma unroll
      for (int n = 0; n < 2; ++n) bfr[n] = LD8(W2 + (wn0 + n * 16 + l15) * 128 + ko);
#pragma unroll
      for (int m = 0; m < 4; ++m)
#pragma unroll
        for (int n = 0; n < 2; ++n) acc2[m][n] = MFMA(af[m], bfr[n], acc2[m][n]);
    }
    const float* b2 = (const float*)(ws + WS_B2);
#pragma unroll
    for (int n = 0; n < 2; ++n) {
      const int col = wn0 + n * 16 + l15;
      const float bias = b2[col];
#pragma unroll
      for (int m = 0; m < 4; ++m)
#pragma unroll
        for (int j = 0; j < 4; ++j) {
          const int row = m * 16 + l4 * 4 + j;
          float v = acc2[m][n][j] + bias;
          v = (v > 0.f) ? v : 0.01f * v;
          h2[row * 264 + col] = f2bf(v);
        }
    }
  }
  __syncthreads();

  // ---------------- GEMM3: imp = sigmoid(...); z = leaky(...) ----------------
  {
    const u16* W3 = (const u16*)(ws + WS_W3);
    const float* b3 = (const float*)(ws + WS_B3);
    f32x4 acc3[4][2];
#pragma unroll
    for (int m = 0; m < 4; ++m)
#pragma unroll
      for (int n = 0; n < 2; ++n) acc3[m][n] = (f32x4){0.f, 0.f, 0.f, 0.f};
#pragma unroll
    for (int kk = 0; kk < 4; ++kk) {
      const int ko = kk * 32 + l4 * 8;
      bf16x8 af[4], bfr[2];
#pragma unroll
      for (int m = 0; m < 4; ++m) af[m] = LD8(h2 + (m * 16 + l15) * 264 + 128 + ko);
#pragma unroll
      for (int n = 0; n < 2; ++n) bfr[n] = LD8(W3 + (64 + wn0 + n * 16 + l15) * 128 + ko);
#pragma unroll
      for (int m = 0; m < 4; ++m)
#pragma unroll
        for (int n = 0; n < 2; ++n) acc3[m][n] = MFMA(af[m], bfr[n], acc3[m][n]);
    }
    u16* impL = (u16*)(smem + LDS_IMP);
#pragma unroll
    for (int n = 0; n < 2; ++n) {
      const int col = wn0 + n * 16 + l15;
      const float bias = b3[64 + col];
#pragma unroll
      for (int m = 0; m < 4; ++m)
#pragma unroll
        for (int j = 0; j < 4; ++j) {
          const int row = m * 16 + l4 * 4 + j;
          float v = acc3[m][n][j] + bias;
          impL[row * 264 + col] = f2bf(1.f / (1.f + expf(-v)));
        }
    }
    // z: waves 0-3 compute 16 rows each, all 64 cols
    if (wave < 4) {
      f32x4 accz[4];
#pragma unroll
      for (int n = 0; n < 4; ++n) accz[n] = (f32x4){0.f, 0.f, 0.f, 0.f};
#pragma unroll
      for (int kk = 0; kk < 4; ++kk) {
        const int ko = kk * 32 + l4 * 8;
        bf16x8 a = LD8(h2 + (wave * 16 + l15) * 264 + ko);
#pragma unroll
        for (int n = 0; n < 4; ++n) {
          bf16x8 b = LD8(W3 + (n * 16 + l15) * 128 + ko);
          accz[n] = MFMA(a, b, accz[n]);
        }
      }
      u16* zb = (u16*)(smem + LDS_ZB);
      float zn[4] = {0.f, 0.f, 0.f, 0.f};
#pragma unroll
      for (int n = 0; n < 4; ++n) {
        const int col = n * 16 + l15;
        const float bias = b3[col];
#pragma unroll
        for (int j = 0; j < 4; ++j) {
          const int row = wave * 16 + l4 * 4 + j;
          float v = accz[n][j] + bias;
          v = (v > 0.f) ? v : 0.01f * v;
          zb[row * 72 + col] = f2bf(v);
          zn[j] += v * v;
        }
      }
#pragma unroll
      for (int j = 0; j < 4; ++j) {
        float v = zn[j];
        v += __shfl_xor(v, 1); v += __shfl_xor(v, 2);
        v += __shfl_xor(v, 4); v += __shfl_xor(v, 8);
        zn[j] = v;
      }
      if (l15 == 0) {
        float* znL = (float*)(smem + LDS_ZN);
#pragma unroll
        for (int j = 0; j < 4; ++j) znL[wave * 16 + l4 * 4 + j] = zn[j];
      }
    }
  }
  __syncthreads();

  // ---------------- GEMM4: sim[64][32] = 1/(|z|^2 - 2 z.p + |p|^2 + 0.5) ----------------
  if (wave < 4) {
    const u16* zb = (const u16*)(smem + LDS_ZB);
    const u16* PT = (const u16*)(ws + WS_PT);
    const float* PN = (const float*)(ws + WS_PN);
    f32x4 accs[2];
#pragma unroll
    for (int n = 0; n < 2; ++n) accs[n] = (f32x4){0.f, 0.f, 0.f, 0.f};
#pragma unroll
    for (int kk = 0; kk < 2; ++kk) {
      const int ko = kk * 32 + l4 * 8;
      bf16x8 a = LD8(zb + (wave * 16 + l15) * 72 + ko);
#pragma unroll
      for (int n = 0; n < 2; ++n) {
        bf16x8 b = LD8(PT + (n * 16 + l15) * 64 + ko);
        accs[n] = MFMA(a, b, accs[n]);
      }
    }
    const float* znL = (const float*)(smem + LDS_ZN);
    float* simL = (float*)(smem + LDS_SIM);
#pragma unroll
    for (int n = 0; n < 2; ++n) {
      const int p = n * 16 + l15;
      const float pn = PN[p];
#pragma unroll
      for (int j = 0; j < 4; ++j) {
        const int row = wave * 16 + l4 * 4 + j;
        simL[row * 33 + p] = 1.f / (znL[row] - 2.f * accs[n][j] + pn);
      }
    }
  }
  __syncthreads();

  // ---------------- c_logits -> run-leader atomics ----------------
  {
    const int r = tid >> 3, c = tid & 7;
    float* cl = (float*)(smem + LDS_CL);
    if (r < valid) {
      const float* simL = (const float*)(smem + LDS_SIM);
      const u16*  impL = (const u16*)(smem + LDS_IMP);
      float s = 0.f;
#pragma unroll
      for (int p = 0; p < 32; ++p) s += simL[r * 33 + p] * bf2f(impL[r * 264 + p * 8 + c]);
      cl[r * 8 + c] = s;
    }
    __syncthreads();
    if (r < valid) {
      const int* segL = (const int*)(smem + LDS_SEG);
      const int sg = segL[r];
      if (r == 0 || segL[r - 1] != sg) {   // leader of a segment run
        float s = 0.f;
        int rr = r;
        do { s += cl[rr * 8 + c]; ++rr; } while (rr < valid && segL[rr] == sg);
        atomicAdd(&seg_sums[sg * 8 + c], s);
        if (c == 0) atomicAdd(&seg_counts[sg], (float)(rr - r));
      }
    }
  }
}

// =======================================================================
__global__ void __launch_bounds__(64) finalize_kernel(const char* __restrict__ ws,
                                                      const int* __restrict__ y,
                                                      float* __restrict__ out)
{
  const int b = threadIdx.x;
  const float* sums = (const float*)(ws + WS_SEGSUM);
  const float* cnts = (const float*)(ws + WS_SEGCNT);
  const float inv = 1.f / cnts[b];
  float lg[8];
  float m = -1e30f;
#pragma unroll
  for (int c = 0; c < 8; ++c) { lg[c] = sums[b * 8 + c] * inv; m = fmaxf(m, lg[c]); }
  float se = 0.f;
#pragma unroll
  for (int c = 0; c < 8; ++c) se += expf(lg[c] - m);
  const float lse = m + logf(se);
#pragma unroll
  for (int c = 0; c < 8; ++c) out[1 + b * 8 + c] = lg[c];
  const int yb = y[b];
  float part = -(lg[yb] - lse);
  for (int o = 1; o < 64; o <<= 1) part += __shfl_xor(part, o);
  if (b == 0) out[0] = part * (1.f / 64.f);
}

// =======================================================================
extern "C" void kernel_launch(void* const* d_in, const int* in_sizes, int n_in,
                              void* d_out, int out_size, void* d_ws, size_t ws_size,
                              hipStream_t stream)
{
  const float* x        = (const float*)d_in[0];
  const int*   y        = (const int*)d_in[1];
  const int*   seg      = (const int*)d_in[2];
  const float* enc_i_w  = (const float*)d_in[3];
  const float* enc_i_b  = (const float*)d_in[4];
  const float* enc_h0_w = (const float*)d_in[5];
  const float* enc_h0_b = (const float*)d_in[6];
  const float* enc_z_w  = (const float*)d_in[7];
  const float* enc_z_b  = (const float*)d_in[8];
  const float* imp_i_w  = (const float*)d_in[9];
  const float* imp_i_b  = (const float*)d_in[10];
  const float* imp_h0_w = (const float*)d_in[11];
  const float* imp_h0_b = (const float*)d_in[12];
  const float* imp_p_w  = (const float*)d_in[13];
  const float* imp_p_b  = (const float*)d_in[14];
  const float* protos   = (const float*)d_in[15];
  char* ws = (char*)d_ws;

  hipMemsetAsync(ws + WS_SEGSUM, 0, 2048 + 256, stream);

  convert_kernel<<<2348, 256, 0, stream>>>(
      enc_i_w, imp_i_w, enc_h0_w, imp_h0_w, enc_z_w, imp_p_w, protos,
      enc_i_b, imp_i_b, enc_h0_b, imp_h0_b, enc_z_b, imp_p_b, ws);

  const int nblocks = (N_CELLS + TM - 1) / TM;  // 782
  fused_main<<<nblocks, 512, LDS_TOTAL, stream>>>(
      x, seg, ws, (float*)(ws + WS_SEGSUM), (float*)(ws + WS_SEGCNT));

  finalize_kernel<<<1, 64, 0, stream>>>(ws, y, (float*)d_out);
}

// Round 11
// 159.994 us; speedup vs baseline: 1.9899x; 1.1300x over previous
//
#include <hip/hip_runtime.h>
#include <math.h>

#define N_CELLS 50000
#define KDIM    2000
#define KPAD    2048
#define BK      128
#define NCHUNK  16
#define TM      64

typedef unsigned short u16;
typedef unsigned int   u32;
typedef __attribute__((ext_vector_type(8))) short          bf16x8;
typedef __attribute__((ext_vector_type(4))) float          f32x4;
typedef __attribute__((ext_vector_type(4))) unsigned short u16x4;

__device__ __forceinline__ u16 f2bf(float f) {
  u32 u = __builtin_bit_cast(u32, f);
  return (u16)((u + 0x7FFFu + ((u >> 16) & 1u)) >> 16);
}
__device__ __forceinline__ float bf2f(u16 h) {
  u32 u = ((u32)h) << 16;
  return __builtin_bit_cast(float, u);
}

// ---------------- workspace layout (bytes) ----------------
// W1 fragment-transposed: entry (r,k) at [ ((k>>3)*256 + r)*8 + (k&7) ]
#define WS_W1     0                     // u16, 256x2048
#define WS_W2     1048576               // u16 [256][128]
#define WS_W3     (WS_W2 + 65536)       // u16 [320][128]
#define WS_PT     (WS_W3 + 81920)       // u16 [32][64]
#define WS_PN     (WS_PT + 4096)        // f32 [32]
#define WS_B1     (WS_PN + 128)         // f32 [256]
#define WS_B2     (WS_B1 + 1024)        // f32 [256]
#define WS_B3     (WS_B2 + 1024)        // f32 [320]
#define WS_SEGSUM (WS_B3 + 1280)        // f32 [64][8]
#define WS_SEGCNT (WS_SEGSUM + 2048)    // f32 [64]

// ---------------- LDS layout (bytes; regions overlap only when dead) ----
#define LDS_SEG  0        // int[64]
#define LDS_SA   256      // 32768   u16 [2][64][128]  (XOR-swizzled dbuf)
#define LDS_H2   256      // 33792   u16 [64][264]     (p2-p3, over dead SA)
#define LDS_SIM  256      // 8448    f32 [64][33]      (p4-p5, over dead H2)
#define LDS_H1   34048    // 33792   u16 [64][264]     (p1-p2)
#define LDS_IMP  34048    // 33792   u16 [64][264]     (p3-p5, over dead H1)
#define LDS_ZB   67840    // 9216    u16 [64][72]      (p3-p4)
#define LDS_CL   67840    // 2048    f32 [64][8]       (p5, over dead ZB)
#define LDS_ZN   77056    // 256     f32 [64]
#define LDS_TOTAL 77312

// =======================================================================
__global__ void __launch_bounds__(256) convert_kernel(
    const float* __restrict__ enc_i_w, const float* __restrict__ imp_i_w,
    const float* __restrict__ enc_h0_w, const float* __restrict__ imp_h0_w,
    const float* __restrict__ enc_z_w, const float* __restrict__ imp_p_w,
    const float* __restrict__ protos,
    const float* __restrict__ enc_i_b, const float* __restrict__ imp_i_b,
    const float* __restrict__ enc_h0_b, const float* __restrict__ imp_h0_b,
    const float* __restrict__ enc_z_b, const float* __restrict__ imp_p_b,
    char* __restrict__ ws)
{
  u16* W1 = (u16*)(ws + WS_W1);
  u16* W2 = (u16*)(ws + WS_W2);
  u16* W3 = (u16*)(ws + WS_W3);
  u16* PT = (u16*)(ws + WS_PT);
  float* PN = (float*)(ws + WS_PN);
  float* b1 = (float*)(ws + WS_B1);
  float* b2 = (float*)(ws + WS_B2);
  float* b3 = (float*)(ws + WS_B3);

  int idx = blockIdx.x * 256 + threadIdx.x;
  if (idx < 524288) {
    int r = idx >> 11, k = idx & 2047;
    float v = 0.f;
    if (k < KDIM) v = (r < 128) ? enc_i_w[r * KDIM + k] : imp_i_w[(r - 128) * KDIM + k];
    W1[((k >> 3) * 256 + r) * 8 + (k & 7)] = f2bf(v);
  } else if (idx < 557056) {
    int j = idx - 524288; int r = j >> 7, k = j & 127;
    float v = (r < 128) ? enc_h0_w[r * 128 + k] : imp_h0_w[(r - 128) * 128 + k];
    W2[j] = f2bf(v);
  } else if (idx < 598016) {
    int j = idx - 557056; int r = j >> 7, k = j & 127;
    float v = (r < 64) ? enc_z_w[r * 128 + k] : imp_p_w[(r - 64) * 128 + k];
    W3[j] = f2bf(v);
  } else if (idx < 600064) {
    int j = idx - 598016;
    PT[j] = f2bf(protos[j]);
  } else if (idx < 600096) {
    int p = idx - 600064;
    float s = 0.f;
    for (int d = 0; d < 64; ++d) { float pb = bf2f(f2bf(protos[p * 64 + d])); s += pb * pb; }
    PN[p] = s + 0.5f;
  } else if (idx < 600352) {
    int j = idx - 600096;
    b1[j] = (j < 128) ? enc_i_b[j] : imp_i_b[j - 128];
  } else if (idx < 600608) {
    int j = idx - 600352;
    b2[j] = (j < 128) ? enc_h0_b[j] : imp_h0_b[j - 128];
  } else if (idx < 600928) {
    int j = idx - 600608;
    b3[j] = (j < 64) ? enc_z_b[j] : imp_p_b[j - 64];
  }
}

// =======================================================================
#define MFMA(a, b, c) __builtin_amdgcn_mfma_f32_16x16x32_bf16((a), (b), (c), 0, 0, 0)
#define LD8(p) (*(const bf16x8*)(const void*)(p))

// ROUND-11: round-7 anchor + ONE change: BLOAD(t+1) issued AFTER the MFMA
// cluster of chunk t (prologue BLOAD(0) before first barrier). r10 showed
// B-latency is on the critical path (halved BLOAD windows cost ~10us);
// issuing next-chunk B behind the MFMAs gives it the A_STORE+barrier+ds_read
// window (~400-600cy) to return -> exposed L2 latency removed, zero extra
// regs unless the compiler renames (then ~96-110, still under the 128 cap).
#define A_GLOAD(dst_, t_) {                                                  \
  const int kb_ = (t_) * BK;                                                 \
  _Pragma("unroll")                                                          \
  for (int j_ = 0; j_ < 4; ++j_) {                                           \
    const int col_ = kb_ + (ac + 8 * j_) * 4;                                \
    dst_[j_] = (arow_ok && col_ < KDIM)                                      \
               ? __builtin_nontemporal_load((const f32x4*)(xr + col_))       \
               : f4z;                                                        \
  } }

#define A_STORE(src_, buf_) {                                                \
  u16* da_ = saB + (buf_) * (TM * BK) + ar * BK;                             \
  _Pragma("unroll")                                                          \
  for (int j_ = 0; j_ < 4; ++j_) {                                           \
    u16x4 pk_;                                                               \
    pk_[0] = f2bf(src_[j_][0]); pk_[1] = f2bf(src_[j_][1]);                  \
    pk_[2] = f2bf(src_[j_][2]); pk_[3] = f2bf(src_[j_][3]);                  \
    const int cu_ = ((ac + 8 * j_) * 4) ^ swW;                               \
    *(u16x4*)(void*)(da_ + cu_) = pk_;                                       \
  } }

#define BLOAD(t_) {                                                          \
  const int tc_ = (t_);                                                      \
  _Pragma("unroll")                                                          \
  for (int q_ = 0; q_ < 8; ++q_)                                             \
    bR[q_] = LD8(bbase + (size_t)(tc_ * 16 + (q_ >> 1) * 4) * 2048 +         \
                 (q_ & 1) * 128);                                            \
  }

#define G1_MFMA(saP_) {                                                      \
  __builtin_amdgcn_s_setprio(1);                                             \
  _Pragma("unroll")                                                          \
  for (int kk_ = 0; kk_ < 4; ++kk_) {                                        \
    const int co_ = (kk_ * 32 + l4 * 8) ^ swR;                               \
    bf16x8 af0 = LD8((saP_) + (l15)      * BK + co_);                        \
    bf16x8 af1 = LD8((saP_) + (16 + l15) * BK + co_);                        \
    bf16x8 af2 = LD8((saP_) + (32 + l15) * BK + co_);                        \
    bf16x8 af3 = LD8((saP_) + (48 + l15) * BK + co_);                        \
    acc1[0][0] = MFMA(af0, bR[kk_*2+0], acc1[0][0]);                         \
    acc1[0][1] = MFMA(af0, bR[kk_*2+1], acc1[0][1]);                         \
    acc1[1][0] = MFMA(af1, bR[kk_*2+0], acc1[1][0]);                         \
    acc1[1][1] = MFMA(af1, bR[kk_*2+1], acc1[1][1]);                         \
    acc1[2][0] = MFMA(af2, bR[kk_*2+0], acc1[2][0]);                         \
    acc1[2][1] = MFMA(af2, bR[kk_*2+1], acc1[2][1]);                         \
    acc1[3][0] = MFMA(af3, bR[kk_*2+0], acc1[3][0]);                         \
    acc1[3][1] = MFMA(af3, bR[kk_*2+1], acc1[3][1]);                         \
  }                                                                          \
  __builtin_amdgcn_s_setprio(0);                                             \
  }

__global__ void __launch_bounds__(512, 4) fused_main(
    const float* __restrict__ x, const int* __restrict__ seg,
    const char* __restrict__ ws,
    float* __restrict__ seg_sums, float* __restrict__ seg_counts)
{
  extern __shared__ char smem[];
  const int tid  = threadIdx.x;
  const int wave = tid >> 6;
  const int lane = tid & 63;
  const int l15  = lane & 15;
  const int l4   = lane >> 4;
  const int row0 = blockIdx.x * TM;
  int valid = N_CELLS - row0; if (valid > TM) valid = TM;
  const int wn0 = wave * 32;        // wave's output-column base (0..224)
  const int ar = tid >> 3;          // A-stage row 0..63
  const int ac = tid & 7;
  const int swW = (ar & 7) << 3;    // XOR swizzle, u16 units (= (row&7)<<4 bytes)
  const int swR = (l15 & 7) << 3;
  const f32x4 f4z = (f32x4){0.f, 0.f, 0.f, 0.f};

  if (tid < TM) {
    int r = row0 + tid;
    ((int*)(smem + LDS_SEG))[tid] = (r < N_CELLS) ? seg[r] : 0;
  }

  // ---------------- GEMM1: h1[64][256] = leaky(x @ W1^T + b1) ----------------
  u16* const saB = (u16*)(smem + LDS_SA);
  const bool arow_ok = (row0 + ar) < N_CELLS;
  const float* xr = x + (size_t)(arow_ok ? (row0 + ar) : 0) * KDIM;
  const u16* const w1t = (const u16*)(ws + WS_W1);
  const u16* const bbase = w1t + (size_t)(l4 * 256 + wn0 + l15) * 8;

  f32x4 aR[4];
  bf16x8 bR[8];
  f32x4 acc1[4][2];
#pragma unroll
  for (int m = 0; m < 4; ++m)
#pragma unroll
    for (int n = 0; n < 2; ++n) acc1[m][n] = (f32x4){0.f, 0.f, 0.f, 0.f};

  A_GLOAD(aR, 0);
  A_STORE(aR, 0);
  BLOAD(0);                          // chunk-0 B in flight across the barrier
  __syncthreads();

  int cur = 0;
  for (int t = 0; t < NCHUNK; ++t) {
    if (t + 1 < NCHUNK) A_GLOAD(aR, t + 1);   // longest-latency loads first
    G1_MFMA(saB + cur * (TM * BK));           // consumes bR (chunk t)
    if (t + 1 < NCHUNK) BLOAD(t + 1);         // next-chunk B behind the MFMAs
    if (t + 1 < NCHUNK) A_STORE(aR, cur ^ 1); // waits aR only (vmcnt(8))
    __syncthreads();
    cur ^= 1;
  }

  // h1 epilogue: bias + leaky -> bf16 LDS
  u16* h1 = (u16*)(smem + LDS_H1);
  {
    const float* b1 = (const float*)(ws + WS_B1);
#pragma unroll
    for (int n = 0; n < 2; ++n) {
      const int col = wn0 + n * 16 + l15;
      const float bias = b1[col];
#pragma unroll
      for (int m = 0; m < 4; ++m)
#pragma unroll
        for (int j = 0; j < 4; ++j) {
          const int row = m * 16 + l4 * 4 + j;
          float v = acc1[m][n][j] + bias;
          v = (v > 0.f) ? v : 0.01f * v;
          h1[row * 264 + col] = f2bf(v);
        }
    }
  }
  __syncthreads();

  // ---------------- GEMM2: h2[64][256] = leaky(h1_branch @ W2^T + b2) ----------------
  u16* h2 = (u16*)(smem + LDS_H2);
  {
    const u16* W2 = (const u16*)(ws + WS_W2);
    const int branch = wave >> 2;   // waves 0-3: enc (h1 cols 0..127), 4-7: imp
    f32x4 acc2[4][2];
#pragma unroll
    for (int m = 0; m < 4; ++m)
#pragma unroll
      for (int n = 0; n < 2; ++n) acc2[m][n] = (f32x4){0.f, 0.f, 0.f, 0.f};
#pragma unroll
    for (int kk = 0; kk < 4; ++kk) {
      const int ko = kk * 32 + l4 * 8;
      bf16x8 af[4], bfr[2];
#pragma unroll
      for (int m = 0; m < 4; ++m) af[m] = LD8(h1 + (m * 16 + l15) * 264 + branch * 128 + ko);
#pragma unroll
      for (int n = 0; n < 2; ++n) bfr[n] = LD8(W2 + (wn0 + n * 16 + l15) * 128 + ko);
#pragma unroll
      for (int m = 0; m < 4; ++m)
#pragma unroll
        for (int n = 0; n < 2; ++n) acc2[m][n] = MFMA(af[m], bfr[n], acc2[m][n]);
    }
    const float* b2 = (const float*)(ws + WS_B2);
#pragma unroll
    for (int n = 0; n < 2; ++n) {
      const int col = wn0 + n * 16 + l15;
      const float bias = b2[col];
#pragma unroll
      for (int m = 0; m < 4; ++m)
#pragma unroll
        for (int j = 0; j < 4; ++j) {
          const int row = m * 16 + l4 * 4 + j;
          float v = acc2[m][n][j] + bias;
          v = (v > 0.f) ? v : 0.01f * v;
          h2[row * 264 + col] = f2bf(v);
        }
    }
  }
  __syncthreads();

  // ---------------- GEMM3: imp = sigmoid(...); z = leaky(...) ----------------
  {
    const u16* W3 = (const u16*)(ws + WS_W3);
    const float* b3 = (const float*)(ws + WS_B3);
    f32x4 acc3[4][2];
#pragma unroll
    for (int m = 0; m < 4; ++m)
#pragma unroll
      for (int n = 0; n < 2; ++n) acc3[m][n] = (f32x4){0.f, 0.f, 0.f, 0.f};
#pragma unroll
    for (int kk = 0; kk < 4; ++kk) {
      const int ko = kk * 32 + l4 * 8;
      bf16x8 af[4], bfr[2];
#pragma unroll
      for (int m = 0; m < 4; ++m) af[m] = LD8(h2 + (m * 16 + l15) * 264 + 128 + ko);
#pragma unroll
      for (int n = 0; n < 2; ++n) bfr[n] = LD8(W3 + (64 + wn0 + n * 16 + l15) * 128 + ko);
#pragma unroll
      for (int m = 0; m < 4; ++m)
#pragma unroll
        for (int n = 0; n < 2; ++n) acc3[m][n] = MFMA(af[m], bfr[n], acc3[m][n]);
    }
    u16* impL = (u16*)(smem + LDS_IMP);
#pragma unroll
    for (int n = 0; n < 2; ++n) {
      const int col = wn0 + n * 16 + l15;
      const float bias = b3[64 + col];
#pragma unroll
      for (int m = 0; m < 4; ++m)
#pragma unroll
        for (int j = 0; j < 4; ++j) {
          const int row = m * 16 + l4 * 4 + j;
          float v = acc3[m][n][j] + bias;
          impL[row * 264 + col] = f2bf(1.f / (1.f + expf(-v)));
        }
    }
    // z: waves 0-3 compute 16 rows each, all 64 cols
    if (wave < 4) {
      f32x4 accz[4];
#pragma unroll
      for (int n = 0; n < 4; ++n) accz[n] = (f32x4){0.f, 0.f, 0.f, 0.f};
#pragma unroll
      for (int kk = 0; kk < 4; ++kk) {
        const int ko = kk * 32 + l4 * 8;
        bf16x8 a = LD8(h2 + (wave * 16 + l15) * 264 + ko);
#pragma unroll
        for (int n = 0; n < 4; ++n) {
          bf16x8 b = LD8(W3 + (n * 16 + l15) * 128 + ko);
          accz[n] = MFMA(a, b, accz[n]);
        }
      }
      u16* zb = (u16*)(smem + LDS_ZB);
      float zn[4] = {0.f, 0.f, 0.f, 0.f};
#pragma unroll
      for (int n = 0; n < 4; ++n) {
        const int col = n * 16 + l15;
        const float bias = b3[col];
#pragma unroll
        for (int j = 0; j < 4; ++j) {
          const int row = wave * 16 + l4 * 4 + j;
          float v = accz[n][j] + bias;
          v = (v > 0.f) ? v : 0.01f * v;
          zb[row * 72 + col] = f2bf(v);
          zn[j] += v * v;
        }
      }
#pragma unroll
      for (int j = 0; j < 4; ++j) {
        float v = zn[j];
        v += __shfl_xor(v, 1); v += __shfl_xor(v, 2);
        v += __shfl_xor(v, 4); v += __shfl_xor(v, 8);
        zn[j] = v;
      }
      if (l15 == 0) {
        float* znL = (float*)(smem + LDS_ZN);
#pragma unroll
        for (int j = 0; j < 4; ++j) znL[wave * 16 + l4 * 4 + j] = zn[j];
      }
    }
  }
  __syncthreads();

  // ---------------- GEMM4: sim[64][32] = 1/(|z|^2 - 2 z.p + |p|^2 + 0.5) ----------------
  if (wave < 4) {
    const u16* zb = (const u16*)(smem + LDS_ZB);
    const u16* PT = (const u16*)(ws + WS_PT);
    const float* PN = (const float*)(ws + WS_PN);
    f32x4 accs[2];
#pragma unroll
    for (int n = 0; n < 2; ++n) accs[n] = (f32x4){0.f, 0.f, 0.f, 0.f};
#pragma unroll
    for (int kk = 0; kk < 2; ++kk) {
      const int ko = kk * 32 + l4 * 8;
      bf16x8 a = LD8(zb + (wave * 16 + l15) * 72 + ko);
#pragma unroll
      for (int n = 0; n < 2; ++n) {
        bf16x8 b = LD8(PT + (n * 16 + l15) * 64 + ko);
        accs[n] = MFMA(a, b, accs[n]);
      }
    }
    const float* znL = (const float*)(smem + LDS_ZN);
    float* simL = (float*)(smem + LDS_SIM);
#pragma unroll
    for (int n = 0; n < 2; ++n) {
      const int p = n * 16 + l15;
      const float pn = PN[p];
#pragma unroll
      for (int j = 0; j < 4; ++j) {
        const int row = wave * 16 + l4 * 4 + j;
        simL[row * 33 + p] = 1.f / (znL[row] - 2.f * accs[n][j] + pn);
      }
    }
  }
  __syncthreads();

  // ---------------- c_logits -> run-leader atomics ----------------
  {
    const int r = tid >> 3, c = tid & 7;
    float* cl = (float*)(smem + LDS_CL);
    if (r < valid) {
      const float* simL = (const float*)(smem + LDS_SIM);
      const u16*  impL = (const u16*)(smem + LDS_IMP);
      float s = 0.f;
#pragma unroll
      for (int p = 0; p < 32; ++p) s += simL[r * 33 + p] * bf2f(impL[r * 264 + p * 8 + c]);
      cl[r * 8 + c] = s;
    }
    __syncthreads();
    if (r < valid) {
      const int* segL = (const int*)(smem + LDS_SEG);
      const int sg = segL[r];
      if (r == 0 || segL[r - 1] != sg) {   // leader of a segment run
        float s = 0.f;
        int rr = r;
        do { s += cl[rr * 8 + c]; ++rr; } while (rr < valid && segL[rr] == sg);
        atomicAdd(&seg_sums[sg * 8 + c], s);
        if (c == 0) atomicAdd(&seg_counts[sg], (float)(rr - r));
      }
    }
  }
}

// =======================================================================
__global__ void __launch_bounds__(64) finalize_kernel(const char* __restrict__ ws,
                                                      const int* __restrict__ y,
                                                      float* __restrict__ out)
{
  const int b = threadIdx.x;
  const float* sums = (const float*)(ws + WS_SEGSUM);
  const float* cnts = (const float*)(ws + WS_SEGCNT);
  const float inv = 1.f / cnts[b];
  float lg[8];
  float m = -1e30f;
#pragma unroll
  for (int c = 0; c < 8; ++c) { lg[c] = sums[b * 8 + c] * inv; m = fmaxf(m, lg[c]); }
  float se = 0.f;
#pragma unroll
  for (int c = 0; c < 8; ++c) se += expf(lg[c] - m);
  const float lse = m + logf(se);
#pragma unroll
  for (int c = 0; c < 8; ++c) out[1 + b * 8 + c] = lg[c];
  const int yb = y[b];
  float part = -(lg[yb] - lse);
  for (int o = 1; o < 64; o <<= 1) part += __shfl_xor(part, o);
  if (b == 0) out[0] = part * (1.f / 64.f);
}

// =======================================================================
extern "C" void kernel_launch(void* const* d_in, const int* in_sizes, int n_in,
                              void* d_out, int out_size, void* d_ws, size_t ws_size,
                              hipStream_t stream)
{
  const float* x        = (const float*)d_in[0];
  const int*   y        = (const int*)d_in[1];
  const int*   seg      = (const int*)d_in[2];
  const float* enc_i_w  = (const float*)d_in[3];
  const float* enc_i_b  = (const float*)d_in[4];
  const float* enc_h0_w = (const float*)d_in[5];
  const float* enc_h0_b = (const float*)d_in[6];
  const float* enc_z_w  = (const float*)d_in[7];
  const float* enc_z_b  = (const float*)d_in[8];
  const float* imp_i_w  = (const float*)d_in[9];
  const float* imp_i_b  = (const float*)d_in[10];
  const float* imp_h0_w = (const float*)d_in[11];
  const float* imp_h0_b = (const float*)d_in[12];
  const float* imp_p_w  = (const float*)d_in[13];
  const float* imp_p_b  = (const float*)d_in[14];
  const float* protos   = (const float*)d_in[15];
  char* ws = (char*)d_ws;

  hipMemsetAsync(ws + WS_SEGSUM, 0, 2048 + 256, stream);

  convert_kernel<<<2348, 256, 0, stream>>>(
      enc_i_w, imp_i_w, enc_h0_w, imp_h0_w, enc_z_w, imp_p_w, protos,
      enc_i_b, imp_i_b, enc_h0_b, imp_h0_b, enc_z_b, imp_p_b, ws);

  const int nblocks = (N_CELLS + TM - 1) / TM;  // 782
  fused_main<<<nblocks, 512, LDS_TOTAL, stream>>>(
      x, seg, ws, (float*)(ws + WS_SEGSUM), (float*)(ws + WS_SEGCNT));

  finalize_kernel<<<1, 64, 0, stream>>>(ws, y, (float*)d_out);
}